// Round 1
// baseline (410.513 us; speedup 1.0000x reference)
//
#include <hip/hip_runtime.h>
#include <hip/hip_bf16.h>
#include <cstddef>

// SelfAttention local-window (K=7) module, MI355X fp32 baseline.
// Pipeline:
//   prep:      fold BN into conv weights -> Weff[256][256], beff[256]
//   gemm<256>: QKV = Weff @ x  (per batch)  -> qkv[b][256][9216]
//   attn:      sim(49x64) + softmax(49) + context(49x128) -> ctx[b][128][9216]
//   gemm<128>: out = ww @ ctx + bw -> d_out[b][256][9216]

#define HW 9216   // 96*96
#define IMH 96
#define IMW 96

__global__ __launch_bounds__(256) void prep_kernel(
    const float* __restrict__ wq, const float* __restrict__ bq,
    const float* __restrict__ gq, const float* __restrict__ betaq,
    const float* __restrict__ mq, const float* __restrict__ vq,
    const float* __restrict__ wk, const float* __restrict__ bk,
    const float* __restrict__ gk, const float* __restrict__ betak,
    const float* __restrict__ mk, const float* __restrict__ vk,
    const float* __restrict__ wv, const float* __restrict__ bv,
    float* __restrict__ Weff, float* __restrict__ beff) {
  int o = blockIdx.x;   // 0..255 output row
  int c = threadIdx.x;  // 0..255 input channel
  float wval, bval;
  if (o < 64) {
    float s = gq[o] * rsqrtf(vq[o] + 1e-5f);
    wval = wq[o * 256 + c] * s;
    bval = (bq[o] - mq[o]) * s + betaq[o];
  } else if (o < 128) {
    int oo = o - 64;
    float s = gk[oo] * rsqrtf(vk[oo] + 1e-5f);
    wval = wk[oo * 256 + c] * s;
    bval = (bk[oo] - mk[oo]) * s + betak[oo];
  } else {
    int oo = o - 128;
    wval = wv[oo * 256 + c];
    bval = bv[oo];
  }
  Weff[o * 256 + c] = wval;
  if (c == 0) beff[o] = bval;
}

// Tiled GEMM: O[b][m][n] = sum_k A[m][k] * X[b][k][n] + bias[m]
// M = 256 rows total, N = 9216 pixels, K = KD (256 or 128).
// 64x64 tile per block, 256 threads, 4x4 micro-tile per thread.
template <int KD>
__global__ __launch_bounds__(256) void gemm_tile(
    const float* __restrict__ A, const float* __restrict__ bias,
    const float* __restrict__ X, float* __restrict__ O) {
  int b = blockIdx.z;
  int m0 = blockIdx.y * 64;
  int n0 = blockIdx.x * 64;
  const float* Xb = X + (size_t)b * KD * HW;
  float* Ob = O + (size_t)b * 256 * HW;

  __shared__ float As[16][68];  // [k][m], stride 68: float4-aligned, 2-way banks (free)
  __shared__ float Bs[16][68];  // [k][n]

  int tid = threadIdx.x;
  int tx = tid & 15;   // pixel quad
  int ty = tid >> 4;   // row quad

  float acc[4][4];
#pragma unroll
  for (int i = 0; i < 4; i++)
#pragma unroll
    for (int j = 0; j < 4; j++) acc[i][j] = 0.f;

  for (int kk = 0; kk < KD; kk += 16) {
#pragma unroll
    for (int i = 0; i < 4; i++) {
      int idx = tid + i * 256;   // 0..1023
      int m = idx >> 4, k = idx & 15;
      As[k][m] = A[(size_t)(m0 + m) * KD + kk + k];
    }
#pragma unroll
    for (int i = 0; i < 4; i++) {
      int idx = tid + i * 256;
      int k = idx >> 6, n = idx & 63;
      Bs[k][n] = Xb[(size_t)(kk + k) * HW + n0 + n];
    }
    __syncthreads();
#pragma unroll
    for (int k = 0; k < 16; k++) {
      float4 av = *(const float4*)&As[k][ty * 4];
      float4 bv4 = *(const float4*)&Bs[k][tx * 4];
      float a_[4] = {av.x, av.y, av.z, av.w};
      float b_[4] = {bv4.x, bv4.y, bv4.z, bv4.w};
#pragma unroll
      for (int i = 0; i < 4; i++)
#pragma unroll
        for (int j = 0; j < 4; j++) acc[i][j] = fmaf(a_[i], b_[j], acc[i][j]);
    }
    __syncthreads();
  }

#pragma unroll
  for (int i = 0; i < 4; i++) {
    int m = m0 + ty * 4 + i;
    float bs = bias[m];
    float4 r;
    r.x = acc[i][0] + bs;
    r.y = acc[i][1] + bs;
    r.z = acc[i][2] + bs;
    r.w = acc[i][3] + bs;
    *(float4*)&Ob[(size_t)m * HW + n0 + tx * 4] = r;
  }
}

// Fused sim + softmax + context. One thread per pixel, 64-thread blocks
// (32x2 spatial tile) -> 288 blocks so all 256 CUs get work.
// qkv layout per batch: rows 0-63 = Q (BN folded), 64-127 = K (BN folded),
// 128-255 = V. All tap offsets di*96+dj are compile-time -> fold into the
// 13-bit signed global_load immediate.
__global__ __launch_bounds__(64) void attn_kernel(
    const float* __restrict__ qkv, float* __restrict__ ctx) {
  int b = blockIdx.z;
  int tw = threadIdx.x & 31;
  int th = threadIdx.x >> 5;           // 0..1
  int w = blockIdx.x * 32 + tw;        // 0..95
  int h = blockIdx.y * 2 + th;         // 0..95
  int pix = h * IMW + w;

  const float* Q = qkv + (size_t)b * 256 * HW;
  const float* K = Q + (size_t)64 * HW;
  const float* V = Q + (size_t)128 * HW;

  float sim[49];
#pragma unroll
  for (int p = 0; p < 49; p++) sim[p] = 0.f;

  // sim[p] = sum_c Q[c,pix] * K[c, pix + off_p]  (unmasked; masked after)
#pragma unroll 4
  for (int c = 0; c < 64; c++) {
    float q = Q[(size_t)c * HW + pix];
    const float* Kc = K + (size_t)c * HW + pix;
#pragma unroll
    for (int p = 0; p < 49; p++) {
      const int di = p / 7 - 3, dj = p % 7 - 3;
      sim[p] = fmaf(q, Kc[di * IMW + dj], sim[p]);
    }
  }

  // zero-pad semantics: padded taps have sim == 0 but stay in the softmax
#pragma unroll
  for (int p = 0; p < 49; p++) {
    const int di = p / 7 - 3, dj = p % 7 - 3;
    bool valid = ((unsigned)(h + di) < (unsigned)IMH) &&
                 ((unsigned)(w + dj) < (unsigned)IMW);
    sim[p] = valid ? sim[p] : 0.f;
  }

  float mx = sim[0];
#pragma unroll
  for (int p = 1; p < 49; p++) mx = fmaxf(mx, sim[p]);
  float ssum = 0.f;
#pragma unroll
  for (int p = 0; p < 49; p++) {
    sim[p] = __expf(sim[p] - mx);
    ssum += sim[p];
  }
  float inv = 1.f / ssum;
#pragma unroll
  for (int p = 0; p < 49; p++) {
    const int di = p / 7 - 3, dj = p % 7 - 3;
    bool valid = ((unsigned)(h + di) < (unsigned)IMH) &&
                 ((unsigned)(w + dj) < (unsigned)IMW);
    sim[p] = valid ? sim[p] * inv : 0.f;   // padded tap: uv == 0 in reference
  }

  float* Cb = ctx + (size_t)b * 128 * HW;
#pragma unroll 2
  for (int c = 0; c < 128; c++) {
    const float* Vc = V + (size_t)c * HW + pix;
    float a0 = 0.f, a1 = 0.f, a2 = 0.f, a3 = 0.f;
#pragma unroll
    for (int p = 0; p < 49; p++) {
      const int di = p / 7 - 3, dj = p % 7 - 3;
      float v = Vc[di * IMW + dj];
      if ((p & 3) == 0) a0 = fmaf(sim[p], v, a0);
      else if ((p & 3) == 1) a1 = fmaf(sim[p], v, a1);
      else if ((p & 3) == 2) a2 = fmaf(sim[p], v, a2);
      else a3 = fmaf(sim[p], v, a3);
    }
    Cb[(size_t)c * HW + pix] = (a0 + a1) + (a2 + a3);
  }
}

extern "C" void kernel_launch(void* const* d_in, const int* in_sizes, int n_in,
                              void* d_out, int out_size, void* d_ws, size_t ws_size,
                              hipStream_t stream) {
  const float* x     = (const float*)d_in[0];
  const float* wq    = (const float*)d_in[1];
  const float* bq    = (const float*)d_in[2];
  const float* gq    = (const float*)d_in[3];
  const float* betaq = (const float*)d_in[4];
  const float* mq    = (const float*)d_in[5];
  const float* vq    = (const float*)d_in[6];
  const float* wk    = (const float*)d_in[7];
  const float* bk    = (const float*)d_in[8];
  const float* gk    = (const float*)d_in[9];
  const float* betak = (const float*)d_in[10];
  const float* mk    = (const float*)d_in[11];
  const float* vk    = (const float*)d_in[12];
  const float* wv    = (const float*)d_in[13];
  const float* bv    = (const float*)d_in[14];
  const float* ww    = (const float*)d_in[15];
  const float* bw    = (const float*)d_in[16];

  float* ws = (float*)d_ws;
  float* Weff = ws;                          // 256*256 = 65536
  float* beff = ws + 65536;                  // 256
  float* qkv  = ws + 65792;                  // 2*256*9216 = 4718592
  float* ctx  = ws + 65792 + 4718592;        // 2*128*9216 = 2359296

  prep_kernel<<<dim3(256), dim3(256), 0, stream>>>(
      wq, bq, gq, betaq, mq, vq, wk, bk, gk, betak, mk, vk, wv, bv, Weff, beff);

  gemm_tile<256><<<dim3(144, 4, 2), dim3(256), 0, stream>>>(Weff, beff, x, qkv);

  attn_kernel<<<dim3(3, 48, 2), dim3(64), 0, stream>>>(qkv, ctx);

  gemm_tile<128><<<dim3(144, 4, 2), dim3(256), 0, stream>>>(ww, bw, ctx, (float*)d_out);
}

// Round 3
// 204.712 us; speedup vs baseline: 2.0053x; 2.0053x over previous
//
#include <hip/hip_runtime.h>
#include <hip/hip_bf16.h>
#include <cstddef>

// SelfAttention local-window (K=7) module, MI355X.
// prep:      fold BN into conv weights -> Weff[256][256], beff[256]
// gemm<256>: QKV = Weff @ x  (per batch)  -> qkv[b][256][9216]
// sim:       sim[b][49][HW]  (wave per 64px x tap -> 14112 waves)
// softmax:   in-place over 49 taps, mask invalid to 0
// ctx:       ctx[b][128][HW] written over dead Q/K region of qkv
// gemm<128>: out = ww @ ctx + bw -> d_out[b][256][9216]

#define HW 9216   // 96*96
#define IMH 96
#define IMW 96

__global__ __launch_bounds__(256) void prep_kernel(
    const float* __restrict__ wq, const float* __restrict__ bq,
    const float* __restrict__ gq, const float* __restrict__ betaq,
    const float* __restrict__ mq, const float* __restrict__ vq,
    const float* __restrict__ wk, const float* __restrict__ bk,
    const float* __restrict__ gk, const float* __restrict__ betak,
    const float* __restrict__ mk, const float* __restrict__ vk,
    const float* __restrict__ wv, const float* __restrict__ bv,
    float* __restrict__ Weff, float* __restrict__ beff) {
  int o = blockIdx.x;   // 0..255 output row
  int c = threadIdx.x;  // 0..255 input channel
  float wval, bval;
  if (o < 64) {
    float s = gq[o] * rsqrtf(vq[o] + 1e-5f);
    wval = wq[o * 256 + c] * s;
    bval = (bq[o] - mq[o]) * s + betaq[o];
  } else if (o < 128) {
    int oo = o - 64;
    float s = gk[oo] * rsqrtf(vk[oo] + 1e-5f);
    wval = wk[oo * 256 + c] * s;
    bval = (bk[oo] - mk[oo]) * s + betak[oo];
  } else {
    int oo = o - 128;
    wval = wv[oo * 256 + c];
    bval = bv[oo];
  }
  Weff[o * 256 + c] = wval;
  if (c == 0) beff[o] = bval;
}

// Tiled GEMM: O[b][m][n] = sum_k A[m][k] * X[b*xbstride + k*HW + n] + bias[m]
template <int KD>
__global__ __launch_bounds__(256) void gemm_tile(
    const float* __restrict__ A, const float* __restrict__ bias,
    const float* __restrict__ X, float* __restrict__ O, long xbstride) {
  int b = blockIdx.z;
  int m0 = blockIdx.y * 64;
  int n0 = blockIdx.x * 64;
  const float* Xb = X + (size_t)b * xbstride;
  float* Ob = O + (size_t)b * 256 * HW;

  __shared__ float As[16][68];
  __shared__ float Bs[16][68];

  int tid = threadIdx.x;
  int tx = tid & 15;
  int ty = tid >> 4;

  float acc[4][4];
#pragma unroll
  for (int i = 0; i < 4; i++)
#pragma unroll
    for (int j = 0; j < 4; j++) acc[i][j] = 0.f;

  for (int kk = 0; kk < KD; kk += 16) {
#pragma unroll
    for (int i = 0; i < 4; i++) {
      int idx = tid + i * 256;
      int m = idx >> 4, k = idx & 15;
      As[k][m] = A[(size_t)(m0 + m) * KD + kk + k];
    }
#pragma unroll
    for (int i = 0; i < 4; i++) {
      int idx = tid + i * 256;
      int k = idx >> 6, n = idx & 63;
      Bs[k][n] = Xb[(size_t)(kk + k) * HW + n0 + n];
    }
    __syncthreads();
#pragma unroll
    for (int k = 0; k < 16; k++) {
      float4 av = *(const float4*)&As[k][ty * 4];
      float4 bv4 = *(const float4*)&Bs[k][tx * 4];
      float a_[4] = {av.x, av.y, av.z, av.w};
      float b_[4] = {bv4.x, bv4.y, bv4.z, bv4.w};
#pragma unroll
      for (int i = 0; i < 4; i++)
#pragma unroll
        for (int j = 0; j < 4; j++) acc[i][j] = fmaf(a_[i], b_[j], acc[i][j]);
    }
    __syncthreads();
  }

#pragma unroll
  for (int i = 0; i < 4; i++) {
    int m = m0 + ty * 4 + i;
    float bs = bias[m];
    float4 r;
    r.x = acc[i][0] + bs;
    r.y = acc[i][1] + bs;
    r.z = acc[i][2] + bs;
    r.w = acc[i][3] + bs;
    *(float4*)&Ob[(size_t)m * HW + n0 + tx * 4] = r;
  }
}

// sim[b][tap][pix] = valid ? sum_c Q[c,pix]*K[c,pix+off] : 0
// wave = 64 consecutive pixels, one tap. grid (144, 49, 2).
__global__ __launch_bounds__(64) void sim_kernel(
    const float* __restrict__ qkv, float* __restrict__ sm) {
  int b = blockIdx.z;
  int tap = blockIdx.y;                    // 0..48
  int pix = blockIdx.x * 64 + threadIdx.x;
  int h = pix / IMW, w = pix % IMW;
  int di = tap / 7 - 3, dj = tap % 7 - 3;
  const float* Qp = qkv + (size_t)b * 256 * HW + pix;
  const float* Kp = Qp + (size_t)64 * HW + di * IMW + dj;

  float a0 = 0.f, a1 = 0.f, a2 = 0.f, a3 = 0.f;
#pragma unroll 8
  for (int c = 0; c < 64; c++) {
    float q = Qp[(size_t)c * HW];
    float k = Kp[(size_t)c * HW];
    if ((c & 3) == 0) a0 = fmaf(q, k, a0);
    else if ((c & 3) == 1) a1 = fmaf(q, k, a1);
    else if ((c & 3) == 2) a2 = fmaf(q, k, a2);
    else a3 = fmaf(q, k, a3);
  }
  float s = (a0 + a1) + (a2 + a3);
  bool valid = ((unsigned)(h + di) < (unsigned)IMH) &&
               ((unsigned)(w + dj) < (unsigned)IMW);
  sm[((size_t)b * 49 + tap) * HW + pix] = valid ? s : 0.f;
}

// In-place masked softmax over the 49 taps. grid (144, 2), block 64.
__global__ __launch_bounds__(64) void softmax_kernel(float* __restrict__ sm) {
  int b = blockIdx.y;
  int pix = blockIdx.x * 64 + threadIdx.x;
  int h = pix / IMW, w = pix % IMW;
  float* S = sm + (size_t)b * 49 * HW + pix;

  float v[49];
#pragma unroll
  for (int p = 0; p < 49; p++) v[p] = S[(size_t)p * HW];

  float mx = v[0];
#pragma unroll
  for (int p = 1; p < 49; p++) mx = fmaxf(mx, v[p]);
  float ssum = 0.f;
#pragma unroll
  for (int p = 0; p < 49; p++) {
    v[p] = __expf(v[p] - mx);
    ssum += v[p];
  }
  float inv = 1.f / ssum;
#pragma unroll
  for (int p = 0; p < 49; p++) {
    const int di = p / 7 - 3, dj = p % 7 - 3;
    bool valid = ((unsigned)(h + di) < (unsigned)IMH) &&
                 ((unsigned)(w + dj) < (unsigned)IMW);
    S[(size_t)p * HW] = valid ? v[p] * inv : 0.f;
  }
}

// ctx[b][c][pix] = sum_p sm[p][pix] * V[c][pix+off_p]
// wave = 64 px handling 4 channels, sm probs in registers.
// grid (144, 32, 2). All 49 tap offsets are compile-time immediates.
__global__ __launch_bounds__(64) void ctx_kernel(
    const float* __restrict__ qkv, const float* __restrict__ sm,
    float* __restrict__ ctx) {
  int b = blockIdx.z;
  int c0 = blockIdx.y * 4;
  int pix = blockIdx.x * 64 + threadIdx.x;

  const float* S = sm + (size_t)b * 49 * HW + pix;
  float p[49];
#pragma unroll
  for (int t = 0; t < 49; t++) p[t] = S[(size_t)t * HW];

  const float* V = qkv + ((size_t)b * 256 + 128) * HW + pix;
  float* Cb = ctx + (size_t)b * 256 * HW + pix;  // overwrites dead Q/K region

#pragma unroll
  for (int cc = 0; cc < 4; cc++) {
    const float* Vc = V + (size_t)(c0 + cc) * HW;
    float a0 = 0.f, a1 = 0.f, a2 = 0.f, a3 = 0.f;
#pragma unroll
    for (int t = 0; t < 49; t++) {
      const int di = t / 7 - 3, dj = t % 7 - 3;
      float v = Vc[di * IMW + dj];
      if ((t & 3) == 0) a0 = fmaf(p[t], v, a0);
      else if ((t & 3) == 1) a1 = fmaf(p[t], v, a1);
      else if ((t & 3) == 2) a2 = fmaf(p[t], v, a2);
      else a3 = fmaf(p[t], v, a3);
    }
    Cb[(size_t)(c0 + cc) * HW] = (a0 + a1) + (a2 + a3);
  }
}

extern "C" void kernel_launch(void* const* d_in, const int* in_sizes, int n_in,
                              void* d_out, int out_size, void* d_ws, size_t ws_size,
                              hipStream_t stream) {
  const float* x     = (const float*)d_in[0];
  const float* wq    = (const float*)d_in[1];
  const float* bq    = (const float*)d_in[2];
  const float* gq    = (const float*)d_in[3];
  const float* betaq = (const float*)d_in[4];
  const float* mq    = (const float*)d_in[5];
  const float* vq    = (const float*)d_in[6];
  const float* wk    = (const float*)d_in[7];
  const float* bk    = (const float*)d_in[8];
  const float* gk    = (const float*)d_in[9];
  const float* betak = (const float*)d_in[10];
  const float* mk    = (const float*)d_in[11];
  const float* vk    = (const float*)d_in[12];
  const float* wv    = (const float*)d_in[13];
  const float* bv    = (const float*)d_in[14];
  const float* ww    = (const float*)d_in[15];
  const float* bw    = (const float*)d_in[16];

  float* ws = (float*)d_ws;
  float* Weff = ws;                                   // 65536
  float* beff = ws + 65536;                           // 256
  float* qkv  = ws + 65792;                           // 2*256*9216 = 4718592
  // 1024-float guard after qkv: masked tail reads (pix+291) land here (finite poison x 0)
  float* sm   = ws + 65792 + 4718592 + 1024;          // 2*49*9216 = 903168
  // ctx is written over the dead Q/K region of qkv (batch stride 256*HW)
  float* ctxb = qkv;

  prep_kernel<<<dim3(256), dim3(256), 0, stream>>>(
      wq, bq, gq, betaq, mq, vq, wk, bk, gk, betak, mk, vk, wv, bv, Weff, beff);

  gemm_tile<256><<<dim3(144, 4, 2), dim3(256), 0, stream>>>(
      Weff, beff, x, qkv, (long)256 * HW);

  sim_kernel<<<dim3(144, 49, 2), dim3(64), 0, stream>>>(qkv, sm);

  softmax_kernel<<<dim3(144, 2), dim3(64), 0, stream>>>(sm);

  ctx_kernel<<<dim3(144, 32, 2), dim3(64), 0, stream>>>(qkv, sm, ctxb);

  gemm_tile<128><<<dim3(144, 4, 2), dim3(256), 0, stream>>>(
      ww, bw, ctxb, (float*)d_out, (long)256 * HW);
}

// Round 15
// 191.137 us; speedup vs baseline: 2.1477x; 1.0710x over previous
//
#include <hip/hip_runtime.h>
#include <hip/hip_bf16.h>
#include <cstddef>

// SelfAttention local-window (K=7) module, MI355X.
// Split-bf16 GEMMs: each fp32 operand decomposed v = hi + lo (bf16 pair,
// ~16 mantissa bits). W@X ~= Whi@Xhi + Whi@Xlo + Wlo@Xhi (3 MFMA segments,
// fp32-equivalent precision; dropped Wlo@Xlo ~ 2^-18 rel).
// prep:        fold BN -> WeffHi/Lo bf16[256][256], beff, wwHi/Lo bf16[256][128]
// tcvt<256>:   x fp32 -> xThi/xTlo bf16[b][HW][256]  (k-contiguous for MFMA)
// mfma<256>:   qkv[b][256][HW]  (3-segment split-bf16 MFMA, fp32 accum)
// sim/softmax/ctx: fp32 attention stage (unchanged from passing round-1 math)
// tcvt<128>:   ctxf -> ctxThi/Lo
// mfma<128>:   out = ww @ ctx + bw -> d_out fp32

#define HW 9216   // 96*96
#define IMH 96
#define IMW 96

using bf16x8 = __attribute__((ext_vector_type(8))) short;   // 8 bf16 in 4 VGPRs
using f32x4  = __attribute__((ext_vector_type(4))) float;   // MFMA accumulator

__device__ inline unsigned short f2bf(float f) {
  // round-to-nearest-even fp32 -> bf16
  unsigned u = __builtin_bit_cast(unsigned, f);
  unsigned r = 0x7fffu + ((u >> 16) & 1u);
  return (unsigned short)((u + r) >> 16);
}
__device__ inline float bf2f(unsigned short h) {
  unsigned u = (unsigned)h << 16;
  return __builtin_bit_cast(float, u);
}

__global__ __launch_bounds__(256) void prep_kernel(
    const float* __restrict__ wq, const float* __restrict__ bq,
    const float* __restrict__ gq, const float* __restrict__ betaq,
    const float* __restrict__ mq, const float* __restrict__ vq,
    const float* __restrict__ wk, const float* __restrict__ bk,
    const float* __restrict__ gk, const float* __restrict__ betak,
    const float* __restrict__ mk, const float* __restrict__ vk,
    const float* __restrict__ wv, const float* __restrict__ bv,
    const float* __restrict__ ww,
    unsigned short* __restrict__ WeffHi, unsigned short* __restrict__ WeffLo,
    float* __restrict__ beff,
    unsigned short* __restrict__ wwHi, unsigned short* __restrict__ wwLo) {
  int o = blockIdx.x;   // 0..255 output row
  int c = threadIdx.x;  // 0..255 input channel
  float wval, bval;
  if (o < 64) {
    float s = gq[o] * rsqrtf(vq[o] + 1e-5f);
    wval = wq[o * 256 + c] * s;
    bval = (bq[o] - mq[o]) * s + betaq[o];
  } else if (o < 128) {
    int oo = o - 64;
    float s = gk[oo] * rsqrtf(vk[oo] + 1e-5f);
    wval = wk[oo * 256 + c] * s;
    bval = (bk[oo] - mk[oo]) * s + betak[oo];
  } else {
    int oo = o - 128;
    wval = wv[oo * 256 + c];
    bval = bv[oo];
  }
  unsigned short hi = f2bf(wval);
  WeffHi[o * 256 + c] = hi;
  WeffLo[o * 256 + c] = f2bf(wval - bf2f(hi));
  if (c == 0) beff[o] = bval;
  if (c < 128) {
    float wv2 = ww[o * 128 + c];
    unsigned short h2 = f2bf(wv2);
    wwHi[o * 128 + c] = h2;
    wwLo[o * 128 + c] = f2bf(wv2 - bf2f(h2));
  }
}

// Transpose + fp32->bf16 hi/lo split: in[b][C][HW] -> hi/lo[b][HW][C]
template <int C>
__global__ __launch_bounds__(256) void tcvt_kernel(
    const float* __restrict__ in,
    unsigned short* __restrict__ outHi, unsigned short* __restrict__ outLo) {
  int b = blockIdx.z;
  int c0 = blockIdx.y * 64;
  int p0 = blockIdx.x * 64;
  const float* ib = in + (size_t)b * C * HW;
  unsigned short* obh = outHi + (size_t)b * HW * C;
  unsigned short* obl = outLo + (size_t)b * HW * C;
  __shared__ float t[64][65];
  int tid = threadIdx.x;
#pragma unroll
  for (int i = 0; i < 16; i++) {
    int idx = tid + i * 256;
    int c = idx >> 6, p = idx & 63;
    t[c][p] = ib[(size_t)(c0 + c) * HW + p0 + p];
  }
  __syncthreads();
#pragma unroll
  for (int i = 0; i < 16; i++) {
    int idx = tid + i * 256;
    int p = idx >> 6, c = idx & 63;
    float v = t[c][p];
    unsigned short hi = f2bf(v);
    size_t o = (size_t)(p0 + p) * C + c0 + c;
    obh[o] = hi;
    obl[o] = f2bf(v - bf2f(hi));
  }
}

// Split-bf16 MFMA GEMM: O[b][m][n] = sum_k W[m][k] * XT[b][n][k] + bias[m]
// 3 segments: (Whi,Xhi), (Whi,Xlo), (Wlo,Xhi) accumulated into the same acc.
// A-operand = XT tile (i = n), B-operand = W (j = m). 128x128 tile, 4 waves,
// BK=64. LDS row stride 72 shorts: 16B-aligned rows, worst 2-way bank (free).
// D-layout (m89-verified): lane l reg r -> i(n) = (l>>4)*4 + r, j(m) = l&15.
template <int KD>
__global__ __launch_bounds__(256) void mfma_gemm(
    const unsigned short* __restrict__ XThi,  // [b][HW][KD] bf16
    const unsigned short* __restrict__ XTlo,
    const unsigned short* __restrict__ WHhi,  // [256][KD]   bf16
    const unsigned short* __restrict__ WHlo,
    const float* __restrict__ bias,           // [256]
    float* __restrict__ O) {                  // [b][256][HW] fp32
  int b = blockIdx.z;
  int n0 = blockIdx.x * 128;
  int m0 = blockIdx.y * 128;
  const unsigned short* XbHi = XThi + (size_t)b * HW * KD;
  const unsigned short* XbLo = XTlo + (size_t)b * HW * KD;

  __shared__ unsigned short Xs[128][72];
  __shared__ unsigned short Ws[128][72];

  int tid = threadIdx.x;
  int wave = tid >> 6;
  int lane = tid & 63;
  int wn = (wave & 1) * 64;   // wave n-offset in tile
  int wm = (wave >> 1) * 64;  // wave m-offset in tile
  int l15 = lane & 15;
  int kg = lane >> 4;         // k-group 0..3

  f32x4 acc[4][4];            // [nf][mf]
#pragma unroll
  for (int i = 0; i < 4; i++)
#pragma unroll
    for (int j = 0; j < 4; j++) acc[i][j] = (f32x4){0.f, 0.f, 0.f, 0.f};

  for (int seg = 0; seg < 3; seg++) {
    const unsigned short* Xsrc = (seg == 1) ? XbLo : XbHi;
    const unsigned short* Wsrc = (seg == 2) ? WHlo : WHhi;
    for (int k0 = 0; k0 < KD; k0 += 64) {
      // stage 128 rows x 64 k of both operands; 16B chunks
#pragma unroll
      for (int i = 0; i < 4; i++) {
        int idx = tid + i * 256;          // 0..1023
        int r = idx >> 3, ch = idx & 7;   // row, 16B chunk
        *(int4*)&Xs[r][ch * 8] = *(const int4*)&Xsrc[(size_t)(n0 + r) * KD + k0 + ch * 8];
        *(int4*)&Ws[r][ch * 8] = *(const int4*)&Wsrc[(size_t)(m0 + r) * KD + k0 + ch * 8];
      }
      __syncthreads();
#pragma unroll
      for (int ks = 0; ks < 2; ks++) {
        bf16x8 a[4], w[4];
#pragma unroll
        for (int f = 0; f < 4; f++) {
          a[f] = *(const bf16x8*)&Xs[wn + f * 16 + l15][ks * 32 + kg * 8];
          w[f] = *(const bf16x8*)&Ws[wm + f * 16 + l15][ks * 32 + kg * 8];
        }
#pragma unroll
        for (int nf = 0; nf < 4; nf++)
#pragma unroll
          for (int mf = 0; mf < 4; mf++)
            acc[nf][mf] = __builtin_amdgcn_mfma_f32_16x16x32_bf16(
                a[nf], w[mf], acc[nf][mf], 0, 0, 0);
      }
      __syncthreads();
    }
  }

  float* Ob = O + (size_t)b * 256 * HW;
#pragma unroll
  for (int mf = 0; mf < 4; mf++) {
    int m = m0 + wm + mf * 16 + l15;
    float bs = bias[m];
#pragma unroll
    for (int nf = 0; nf < 4; nf++) {
      int n = n0 + wn + nf * 16 + kg * 4;
      f32x4 v = acc[nf][mf];
      float4 r4;
      r4.x = v[0] + bs; r4.y = v[1] + bs; r4.z = v[2] + bs; r4.w = v[3] + bs;
      *(float4*)&Ob[(size_t)m * HW + n] = r4;
    }
  }
}

// sim[b][tap][pix] = valid ? sum_c Q[c,pix]*K[c,pix+off] : 0
__global__ __launch_bounds__(64) void sim_kernel(
    const float* __restrict__ qkv, float* __restrict__ sm) {
  int b = blockIdx.z;
  int tap = blockIdx.y;                    // 0..48
  int pix = blockIdx.x * 64 + threadIdx.x;
  int h = pix / IMW, w = pix % IMW;
  int di = tap / 7 - 3, dj = tap % 7 - 3;
  const float* Qp = qkv + (size_t)b * 256 * HW + pix;
  const float* Kp = Qp + (size_t)64 * HW + di * IMW + dj;

  float a0 = 0.f, a1 = 0.f, a2 = 0.f, a3 = 0.f;
#pragma unroll 8
  for (int c = 0; c < 64; c++) {
    float q = Qp[(size_t)c * HW];
    float k = Kp[(size_t)c * HW];
    if ((c & 3) == 0) a0 = fmaf(q, k, a0);
    else if ((c & 3) == 1) a1 = fmaf(q, k, a1);
    else if ((c & 3) == 2) a2 = fmaf(q, k, a2);
    else a3 = fmaf(q, k, a3);
  }
  float s = (a0 + a1) + (a2 + a3);
  bool valid = ((unsigned)(h + di) < (unsigned)IMH) &&
               ((unsigned)(w + dj) < (unsigned)IMW);
  sm[((size_t)b * 49 + tap) * HW + pix] = valid ? s : 0.f;
}

// In-place masked softmax over the 49 taps.
__global__ __launch_bounds__(64) void softmax_kernel(float* __restrict__ sm) {
  int b = blockIdx.y;
  int pix = blockIdx.x * 64 + threadIdx.x;
  int h = pix / IMW, w = pix % IMW;
  float* S = sm + (size_t)b * 49 * HW + pix;

  float v[49];
#pragma unroll
  for (int p = 0; p < 49; p++) v[p] = S[(size_t)p * HW];

  float mx = v[0];
#pragma unroll
  for (int p = 1; p < 49; p++) mx = fmaxf(mx, v[p]);
  float ssum = 0.f;
#pragma unroll
  for (int p = 0; p < 49; p++) {
    v[p] = __expf(v[p] - mx);
    ssum += v[p];
  }
  float inv = 1.f / ssum;
#pragma unroll
  for (int p = 0; p < 49; p++) {
    const int di = p / 7 - 3, dj = p % 7 - 3;
    bool valid = ((unsigned)(h + di) < (unsigned)IMH) &&
                 ((unsigned)(w + dj) < (unsigned)IMW);
    S[(size_t)p * HW] = valid ? v[p] * inv : 0.f;
  }
}

// ctxf[b][c][pix] = sum_p sm[p][pix] * V[c][pix+off_p]
__global__ __launch_bounds__(64) void ctx_kernel(
    const float* __restrict__ qkv, const float* __restrict__ sm,
    float* __restrict__ ctx) {
  int b = blockIdx.z;
  int c0 = blockIdx.y * 4;
  int pix = blockIdx.x * 64 + threadIdx.x;

  const float* S = sm + (size_t)b * 49 * HW + pix;
  float p[49];
#pragma unroll
  for (int t = 0; t < 49; t++) p[t] = S[(size_t)t * HW];

  const float* V = qkv + ((size_t)b * 256 + 128) * HW + pix;
  float* Cb = ctx + (size_t)b * 128 * HW + pix;

#pragma unroll
  for (int cc = 0; cc < 4; cc++) {
    const float* Vc = V + (size_t)(c0 + cc) * HW;
    float a0 = 0.f, a1 = 0.f, a2 = 0.f, a3 = 0.f;
#pragma unroll
    for (int t = 0; t < 49; t++) {
      const int di = t / 7 - 3, dj = t % 7 - 3;
      float v = Vc[di * IMW + dj];
      if ((t & 3) == 0) a0 = fmaf(p[t], v, a0);
      else if ((t & 3) == 1) a1 = fmaf(p[t], v, a1);
      else if ((t & 3) == 2) a2 = fmaf(p[t], v, a2);
      else a3 = fmaf(p[t], v, a3);
    }
    Cb[(size_t)(c0 + cc) * HW] = (a0 + a1) + (a2 + a3);
  }
}

extern "C" void kernel_launch(void* const* d_in, const int* in_sizes, int n_in,
                              void* d_out, int out_size, void* d_ws, size_t ws_size,
                              hipStream_t stream) {
  const float* x     = (const float*)d_in[0];
  const float* wq    = (const float*)d_in[1];
  const float* bq    = (const float*)d_in[2];
  const float* gq    = (const float*)d_in[3];
  const float* betaq = (const float*)d_in[4];
  const float* mq    = (const float*)d_in[5];
  const float* vq    = (const float*)d_in[6];
  const float* wk    = (const float*)d_in[7];
  const float* bk    = (const float*)d_in[8];
  const float* gk    = (const float*)d_in[9];
  const float* betak = (const float*)d_in[10];
  const float* mk    = (const float*)d_in[11];
  const float* vk    = (const float*)d_in[12];
  const float* wv    = (const float*)d_in[13];
  const float* bv    = (const float*)d_in[14];
  const float* ww    = (const float*)d_in[15];
  const float* bw    = (const float*)d_in[16];

  char* base = (char*)d_ws;
  unsigned short* WeffHi = (unsigned short*)(base + 0);         // 131072 B
  unsigned short* WeffLo = (unsigned short*)(base + 131072);    // 131072 B
  unsigned short* wwHi   = (unsigned short*)(base + 262144);    // 65536 B
  unsigned short* wwLo   = (unsigned short*)(base + 327680);    // 65536 B
  float*          beff   = (float*)(base + 393216);             // 1024 B
  unsigned short* xThi   = (unsigned short*)(base + 397312);    // 9437184 B
  unsigned short* xTlo   = (unsigned short*)(base + 9834496);   // 9437184 B
  float*          qkv    = (float*)(base + 19271680);           // 18874368 B
  // 4096 B guard after qkv: masked tail reads (pix+291) land here (finite x 0)
  float*          smb    = (float*)(base + 38150144);           // 3612672 B
  float*          ctxf   = (float*)(base + 41762816);           // 9437184 B
  unsigned short* ctxThi = (unsigned short*)(base + 51200000);  // 4718592 B
  unsigned short* ctxTlo = (unsigned short*)(base + 55918592);  // 4718592 B

  prep_kernel<<<dim3(256), dim3(256), 0, stream>>>(
      wq, bq, gq, betaq, mq, vq, wk, bk, gk, betak, mk, vk, wv, bv, ww,
      WeffHi, WeffLo, beff, wwHi, wwLo);

  tcvt_kernel<256><<<dim3(144, 4, 2), dim3(256), 0, stream>>>(x, xThi, xTlo);

  mfma_gemm<256><<<dim3(72, 2, 2), dim3(256), 0, stream>>>(
      xThi, xTlo, WeffHi, WeffLo, beff, qkv);

  sim_kernel<<<dim3(144, 49, 2), dim3(64), 0, stream>>>(qkv, smb);

  softmax_kernel<<<dim3(144, 2), dim3(64), 0, stream>>>(smb);

  ctx_kernel<<<dim3(144, 32, 2), dim3(64), 0, stream>>>(qkv, smb, ctxf);

  tcvt_kernel<128><<<dim3(144, 2, 2), dim3(256), 0, stream>>>(ctxf, ctxThi, ctxTlo);

  mfma_gemm<128><<<dim3(72, 2, 2), dim3(256), 0, stream>>>(
      ctxThi, ctxTlo, wwHi, wwLo, bw, (float*)d_out);
}